// Round 10
// baseline (181.003 us; speedup 1.0000x reference)
//
#include <hip/hip_runtime.h>
#include <math.h>

// ---------------------------------------------------------------------------
// SlidingWindowGQA: x[2,2048,2048] f32, wq[2048,2048], wk/wv[2048,512], wo[2048,2048]
// out f32 [2,2048,2048].  B=2 S=2048 H=16 KVH=4 D=128 WINDOW=512.
// R10: R9 + GEMM upgraded to 3-buffer ring with counted-vmcnt barrier gate:
//      stage(t+2) AFTER the barrier (WAR via barrier), WAITV(4) before each raw
//      s_barrier forces tile t+1's staging block-wide while tile t+2's loads
//      stay in flight. Single-variable change vs R9; reads/MFMA identical.
// ---------------------------------------------------------------------------

typedef unsigned short u16;
typedef __attribute__((ext_vector_type(4))) float f32x4;
typedef __attribute__((ext_vector_type(8))) __bf16 bf16x8;
typedef __attribute__((ext_vector_type(4))) __bf16 bf16x4;
typedef __attribute__((ext_vector_type(4))) short s16x4;
typedef __attribute__((ext_vector_type(8))) unsigned short u16x8;
typedef __attribute__((ext_vector_type(4))) unsigned short u16x4;

#define DEV static __device__ __forceinline__
#define WAITV(n) asm volatile("s_waitcnt vmcnt(" #n ")" ::: "memory")

DEV float bf2f(u16 h) {
    union { unsigned int i; float f; } x;
    x.i = ((unsigned int)h) << 16;
    return x.f;
}
DEV u16 f2bf(float f) {
    union { float f; unsigned int i; } x;
    x.f = f;
    unsigned int u = x.i;
    return (u16)((u + 0x7FFFu + ((u >> 16) & 1u)) >> 16);
}

DEV f32x4 mfma32(bf16x8 a, bf16x8 b, f32x4 c) {
    return __builtin_amdgcn_mfma_f32_16x16x32_bf16(a, b, c, 0, 0, 0);
}
DEV f32x4 mfma16(bf16x4 a, bf16x4 b, f32x4 c) {
#if __has_builtin(__builtin_amdgcn_mfma_f32_16x16x16_bf16)
    return __builtin_amdgcn_mfma_f32_16x16x16_bf16(a, b, c, 0, 0, 0);
#else
    union { bf16x4 v; s16x4 s; } ua, ub;
    ua.v = a; ub.v = b;
    return __builtin_amdgcn_mfma_f32_16x16x16bf16_1k(ua.s, ub.s, c, 0, 0, 0);
#endif
}

DEV void gload_lds16(const void* g, void* lds) {
    __builtin_amdgcn_global_load_lds(
        (const __attribute__((address_space(1))) unsigned int*)g,
        (__attribute__((address_space(3))) unsigned int*)lds, 16, 0, 0);
}

// ---------------------------------------------------------------------------
// Fused prep: sincos table + x->bf16 cast + 4x weight convert/transpose.
__global__ __launch_bounds__(256) void prep_kernel(const float* x, const float* wq,
                                                   const float* wk, const float* wv,
                                                   const float* wo, u16* xb, u16* wAll,
                                                   u16* woT, float* ct, float* st) {
    __shared__ float tile[32][33];
    const int bid = blockIdx.x;
    const int tid = threadIdx.x;
    if (bid < 512) {
        int idx = bid * 256 + tid;                 // 131072
        int s = idx >> 6, d = idx & 63;
        float inv = exp2f(-(float)d * (13.287712379549449f / 64.f));
        float a = (float)s * inv;
        float sv, cv;
        sincosf(a, &sv, &cv);
        ct[idx] = cv;
        st[idx] = sv;
        return;
    }
    if (bid < 8704) {
        int i = (bid - 512) * 256 + tid;           // 2097152 float4s
        float4 v = ((const float4*)x)[i];
        u16x4 o;
        o[0] = f2bf(v.x); o[1] = f2bf(v.y); o[2] = f2bf(v.z); o[3] = f2bf(v.w);
        ((u16x4*)xb)[i] = o;
        return;
    }
    // convT: f32 [R][C](ldi) -> bf16 [C][R](ld 2048)
    int r = bid - 8704;
    const float* in;
    u16* out;
    int ldi, bx, by;
    if (r < 4096) { in = wq; out = wAll; ldi = 2048; bx = r & 63; by = r >> 6; }
    else if (r < 5120) { r -= 4096; in = wk; out = wAll + (long)2048 * 2048; ldi = 512; bx = r & 15; by = r >> 4; }
    else if (r < 6144) { r -= 5120; in = wv; out = wAll + (long)2560 * 2048; ldi = 512; bx = r & 15; by = r >> 4; }
    else { r -= 6144; in = wo; out = woT; ldi = 2048; bx = r & 63; by = r >> 6; }
    int cc = tid & 31, rb = tid >> 5;
    long r0 = (long)by * 32, c0 = (long)bx * 32;
#pragma unroll
    for (int i = 0; i < 4; i++)
        tile[rb + i * 8][cc] = in[(r0 + rb + i * 8) * (long)ldi + c0 + cc];
    __syncthreads();
#pragma unroll
    for (int i = 0; i < 4; i++)
        out[(c0 + rb + i * 8) * 2048L + r0 + cc] = f2bf(tile[cc][rb + i * 8]);
}

// Merged K-RoPE + V-transpose (Q-rope lives in attn).
__global__ __launch_bounds__(256) void ropeKT_kernel(u16* QKV, u16* Vt,
                                                     const float* ct, const float* st) {
    __shared__ u16 tile[32][33];
    const int bid = blockIdx.x;
    const int tid = threadIdx.x;
    if (bid < 512) {
        int idx = bid * 256 + tid;                 // 131072
        int m = idx >> 5;
        int rest = idx & 31;
        int hoff = 2048 + (rest >> 3) * 128;
        int d0 = (rest & 7) * 8;
        int s = m & 2047;
        u16* p1 = QKV + (long)m * 3072 + hoff + d0;
        u16* p2 = p1 + 64;
        u16x8 v1 = *(const u16x8*)p1;
        u16x8 v2 = *(const u16x8*)p2;
        const float* cp = ct + s * 64 + d0;
        const float* sp = st + s * 64 + d0;
        u16x8 o1, o2;
#pragma unroll
        for (int j = 0; j < 8; j++) {
            float x1 = bf2f(v1[j]), x2 = bf2f(v2[j]);
            float cc = cp[j], ss = sp[j];
            o1[j] = f2bf(x1 * cc - x2 * ss);
            o2[j] = f2bf(x2 * cc + x1 * ss);
        }
        *(u16x8*)p1 = o1;
        *(u16x8*)p2 = o2;
        return;
    }
    int r = bid - 512;                             // 2048 transpose blocks
    int z = r >> 10;
    int rr = r & 1023;
    int bx = rr & 15, by = rr >> 4;
    const u16* in = QKV + 2560 + (long)z * 2048 * 3072;
    u16* out = Vt + (long)z * 512 * 2048;
    int cc = tid & 31, rb = tid >> 5;
    long r0 = (long)by * 32, c0 = (long)bx * 32;
#pragma unroll
    for (int i = 0; i < 4; i++)
        tile[rb + i * 8][cc] = in[(r0 + rb + i * 8) * 3072 + c0 + cc];
    __syncthreads();
#pragma unroll
    for (int i = 0; i < 4; i++)
        out[(c0 + rb + i * 8) * 2048L + r0 + cc] = tile[cc][rb + i * 8];
}

// ---------------------------------------------------------------------------
// GEMM: C[M][N] = A[M][K](bf16,row) * Bt[N][K](bf16,row)^T. 128x128, BK=32,
// 4 waves (2x2). R10: 3-buffer LDS ring + counted-vmcnt barrier gate.
//   tile t body: stage(t+2)->buf[(t+2)%3]   (WAR-safe: its readers, tile t-1,
//                                            finished before the barrier we
//                                            just passed)
//                reads buf[t%3] + 16 MFMA   (lgkm handled by compiler)
//                WAITV(4): force OWN stage(t+1) calls, leave stage(t+2) out
//                s_barrier + sched_barrier  -> tile t+1 reads are safe
// Every wave forces its tile-t+1 staging before the barrier preceding those
// reads => block-wide visibility without a full vmcnt(0) drain.
template <bool OUT_BF16>
__global__ __launch_bounds__(256) void gemm_bt_kernel(const u16* A, const u16* Bt, void* Cout,
                                                      int M, int N, int K) {
    __shared__ u16 As[3][128 * 32];
    __shared__ u16 Bs[3][128 * 32];
    const int tid = threadIdx.x;
    const int w = tid >> 6, l = tid & 63, g = l >> 4, c = l & 15;
    const int wm = w >> 1, wn = w & 1;
    const long m0 = (long)blockIdx.y * 128, n0 = (long)blockIdx.x * 128;
    const int nk = K >> 5;

    f32x4 acc[4][4];
    const f32x4 zero = {0.f, 0.f, 0.f, 0.f};
#pragma unroll
    for (int i = 0; i < 4; i++)
#pragma unroll
        for (int j = 0; j < 4; j++) acc[i][j] = zero;

    auto stage = [&](int buf, int kt) {
#pragma unroll
        for (int i = 0; i < 2; i++) {
            int o = (i * 256 + tid) * 16;
            int row = o >> 6;
            int cl = ((o >> 4) & 3) ^ ((row >> 1) & 3);
            gload_lds16(A + (m0 + row) * (long)K + kt * 32 + cl * 8,
                        (void*)&As[buf][(i * 256 + w * 64) * 8]);
        }
#pragma unroll
        for (int i = 0; i < 2; i++) {
            int o = (i * 256 + tid) * 16;
            int row = o >> 6;
            int cl = ((o >> 4) & 3) ^ ((row >> 1) & 3);
            gload_lds16(Bt + (n0 + row) * (long)K + kt * 32 + cl * 8,
                        (void*)&Bs[buf][(i * 256 + w * 64) * 8]);
        }
    };

    // prologue: tiles 0,1 in flight; force tile 0 (leave tile 1's 4 calls).
    stage(0, 0);
    stage(1, 1);
    WAITV(4);
    __builtin_amdgcn_s_barrier();
    __builtin_amdgcn_sched_barrier(0);

    int b0 = 0;
    for (int kt = 0; kt < nk; ++kt) {
        int b2 = b0 + 2; if (b2 >= 3) b2 -= 3;
        if (kt + 2 < nk) stage(b2, kt + 2);

        bf16x8 af[4], bf[4];
#pragma unroll
        for (int i = 0; i < 4; i++) {
            int rowa = wm * 64 + i * 16 + c;
            int cha = g ^ ((rowa >> 1) & 3);
            af[i] = *(const bf16x8*)&As[b0][rowa * 32 + cha * 8];
            int rowb = wn * 64 + i * 16 + c;
            int chb = g ^ ((rowb >> 1) & 3);
            bf[i] = *(const bf16x8*)&Bs[b0][rowb * 32 + chb * 8];
        }
#pragma unroll
        for (int i = 0; i < 4; i++)
#pragma unroll
            for (int j = 0; j < 4; j++) acc[i][j] = mfma32(af[i], bf[j], acc[i][j]);

        if (kt + 2 < nk) { WAITV(4); }             // force stage(kt+1)
        else if (kt + 1 < nk) { WAITV(0); }        // last prefetch: force fully
        if (kt + 1 < nk) {
            __builtin_amdgcn_s_barrier();
            __builtin_amdgcn_sched_barrier(0);
        }
        b0 = (b0 + 1 == 3) ? 0 : b0 + 1;
    }

#pragma unroll
    for (int i = 0; i < 4; i++)
#pragma unroll
        for (int j = 0; j < 4; j++) {
            long row0 = m0 + wm * 64 + i * 16 + g * 4;
            long col = n0 + wn * 64 + j * 16 + c;
#pragma unroll
            for (int r = 0; r < 4; r++) {
                float v = acc[i][j][r];
                if (OUT_BF16)
                    ((u16*)Cout)[(row0 + r) * (long)N + col] = f2bf(v);
                else
                    ((float*)Cout)[(row0 + r) * (long)N + col] = v;
            }
        }
}

// ---------------------------------------------------------------------------
// Flash sliding-window GQA (R9, unchanged): double-buffered, Q-RoPE in regs,
// T13 defer-max.
#define ATT_SCALE 0.08838834764831845f
#define L2E 1.4426950408889634f

__global__ __launch_bounds__(512) void attn_kernel(const u16* QKV, const u16* Vt, u16* AO,
                                                   const float* ct, const float* st) {
    __shared__ u16 Ks[2][64 * 128];
    __shared__ u16 Vs[2][128 * 64];
    const int tid = threadIdx.x;
    const int w = tid >> 6, l = tid & 63, g = l >> 4, c = l & 15;
    const int h = blockIdx.y;
    const int b = blockIdx.z;
    const int kvh = h >> 2;
    const int q0 = blockIdx.x * 128;
    const int qb = q0 + w * 16;

    bf16x8 bq[4];
    {
        const u16* qrow = QKV + (long)(b * 2048 + qb + c) * 3072 + h * 128;
#pragma unroll
        for (int kc = 0; kc < 4; kc++) bq[kc] = *(const bf16x8*)(qrow + kc * 32 + g * 8);
        const float* cb = ct + (qb + c) * 64 + g * 8;
        const float* sb = st + (qb + c) * 64 + g * 8;
#pragma unroll
        for (int kc = 0; kc < 2; kc++) {
            union { bf16x8 v; u16x8 u; } lo, hi;
            lo.v = bq[kc]; hi.v = bq[kc + 2];
#pragma unroll
            for (int j = 0; j < 8; j++) {
                float x1 = bf2f(lo.u[j]), x2 = bf2f(hi.u[j]);
                float cc = cb[kc * 32 + j], ss = sb[kc * 32 + j];
                lo.u[j] = f2bf(x1 * cc - x2 * ss);
                hi.u[j] = f2bf(x2 * cc + x1 * ss);
            }
            bq[kc] = lo.v; bq[kc + 2] = hi.v;
        }
    }

    f32x4 acc_o[8];
    const f32x4 zero = {0.f, 0.f, 0.f, 0.f};
#pragma unroll
    for (int i = 0; i < 8; i++) acc_o[i] = zero;
    float m_run = -3.0e38f, l_run = 0.f;

    const int t_lo = (q0 > 511) ? ((q0 - 511) >> 6) : 0;
    const int t_hi = (q0 + 127) >> 6;

    auto stage = [&](int sb_, int t) {
        const int kv0 = t * 64;
#pragma unroll
        for (int i = 0; i < 2; i++) {
            int o = (i * 512 + tid) * 16;
            int key = o >> 8;
            int cl = ((o >> 4) & 15) ^ (key & 15);
            gload_lds16(QKV + (long)(b * 2048 + kv0 + key) * 3072 + 2048 + kvh * 128 + cl * 8,
                        (void*)&Ks[sb_][(i * 512 + w * 64) * 8]);
        }
#pragma unroll
        for (int i = 0; i < 2; i++) {
            int o = (i * 512 + tid) * 16;
            int d = o >> 7;
            int cl = ((o >> 4) & 7) ^ (d & 7);
            gload_lds16(Vt + (long)((b * 4 + kvh) * 128 + d) * 2048 + kv0 + cl * 8,
                        (void*)&Vs[sb_][(i * 512 + w * 64) * 8]);
        }
    };

    stage(0, t_lo);
    __syncthreads();
    int buf = 0;

    for (int t = t_lo; t <= t_hi; ++t) {
        const int kv0 = t * 64;
        if (t < t_hi) stage(buf ^ 1, t + 1);

        const bool active = (kv0 <= qb + 15) && (kv0 + 63 >= qb - 511);
        if (active) {
            f32x4 sacc[4];
#pragma unroll
            for (int n = 0; n < 4; n++) {
                sacc[n] = zero;
#pragma unroll
                for (int kc = 0; kc < 4; kc++) {
                    int row = n * 16 + c;
                    int ch = (kc * 4 + g) ^ c;
                    bf16x8 kf = *(const bf16x8*)&Ks[buf][row * 128 + ch * 8];
                    sacc[n] = mfma32(kf, bq[kc], sacc[n]);
                }
            }

            const bool edge = (kv0 + 63 > qb) || (kv0 < qb + 15 - 511);
            float p[4][4];
            float m_tile = -3.0e38f;
#pragma unroll
            for (int n = 0; n < 4; n++)
#pragma unroll
                for (int r = 0; r < 4; r++) {
                    float s = sacc[n][r] * ATT_SCALE;
                    if (edge) {
                        int j = kv0 + n * 16 + 4 * g + r;
                        int q = qb + c;
                        if (j > q || j < q - 511) s = -__builtin_inff();
                    }
                    p[n][r] = s;
                    m_tile = fmaxf(m_tile, s);
                }
            m_tile = fmaxf(m_tile, __shfl_xor(m_tile, 16));
            m_tile = fmaxf(m_tile, __shfl_xor(m_tile, 32));

            const bool keep = __all(m_tile - m_run <= 8.f);
            const float m_new = keep ? m_run : fmaxf(m_run, m_tile);

            float lsum = 0.f;
#pragma unroll
            for (int n = 0; n < 4; n++)
#pragma unroll
                for (int r = 0; r < 4; r++) {
                    float e = exp2f((p[n][r] - m_new) * L2E);
                    p[n][r] = e;
                    lsum += e;
                }
            lsum += __shfl_xor(lsum, 16);
            lsum += __shfl_xor(lsum, 32);

            if (!keep) {
                float alpha = exp2f((m_run - m_new) * L2E);
                l_run = l_run * alpha + lsum;
                m_run = m_new;
                float alpha_r[4];
#pragma unroll
                for (int r = 0; r < 4; r++) alpha_r[r] = __shfl(alpha, (g << 4) + 4 * g + r);
#pragma unroll
                for (int dn = 0; dn < 8; dn++) {
                    f32x4 t2 = acc_o[dn];
                    t2[0] *= alpha_r[0]; t2[1] *= alpha_r[1];
                    t2[2] *= alpha_r[2]; t2[3] *= alpha_r[3];
                    acc_o[dn] = t2;
                }
            } else {
                l_run += lsum;
            }

            bf16x4 ap[4];
#pragma unroll
            for (int n = 0; n < 4; n++) {
                union { u16x4 u; bf16x4 b; } pk;
                pk.u[0] = f2bf(p[n][0]); pk.u[1] = f2bf(p[n][1]);
                pk.u[2] = f2bf(p[n][2]); pk.u[3] = f2bf(p[n][3]);
                ap[n] = pk.b;
            }

#pragma unroll
            for (int n = 0; n < 4; n++)
#pragma unroll
                for (int dn = 0; dn < 8; dn++) {
                    int row = dn * 16 + c;
                    int ch = (2 * n + (g >> 1)) ^ (c & 7);
                    bf16x4 vf = *(const bf16x4*)&Vs[buf][row * 64 + ch * 8 + (g & 1) * 4];
                    acc_o[dn] = mfma16(ap[n], vf, acc_o[dn]);
                }
        }
        __syncthreads();
        buf ^= 1;
    }

    float lr[4];
#pragma unroll
    for (int r = 0; r < 4; r++) {
        float lq = __shfl(l_run, (g << 4) + 4 * g + r);
        lr[r] = 1.f / lq;
    }
#pragma unroll
    for (int dn = 0; dn < 8; dn++)
#pragma unroll
        for (int r = 0; r < 4; r++) {
            long row = (long)(b * 2048 + qb + 4 * g + r);
            AO[row * 2048 + h * 128 + dn * 16 + c] = f2bf(acc_o[dn][r] * lr[r]);
        }
}

// ---------------------------------------------------------------------------
extern "C" void kernel_launch(void* const* d_in, const int* in_sizes, int n_in,
                              void* d_out, int out_size, void* d_ws, size_t ws_size,
                              hipStream_t stream) {
    const float* x = (const float*)d_in[0];
    const float* wq = (const float*)d_in[1];
    const float* wk = (const float*)d_in[2];
    const float* wv = (const float*)d_in[3];
    const float* wo = (const float*)d_in[4];
    float* out = (float*)d_out;

    char* ws = (char*)d_ws;
    u16* xb = (u16*)(ws);                         // [4096][2048]        16.78 MB
    u16* wAll = (u16*)(ws + 16777216);            // [3072][2048] (BT)   12.58 MB
    u16* woT = (u16*)(ws + 29360128);             // [2048][2048] (BT)    8.39 MB
    u16* QKV = (u16*)(ws + 37748736);             // [4096][3072]        25.17 MB
    u16* Vt = (u16*)(ws + 62914560);              // [1024][2048]         4.19 MB
    u16* AO = (u16*)(ws + 67108864);              // [4096][2048]        16.78 MB
    float* ct = (float*)(ws + 83886080);          // [2048][64]
    float* st = (float*)(ws + 84410368);          // [2048][64]

    prep_kernel<<<18944, 256, 0, stream>>>(x, wq, wk, wv, wo, xb, wAll, woT, ct, st);

    // QKV = xb @ wAll^T
    gemm_bt_kernel<true><<<dim3(24, 32), 256, 0, stream>>>(xb, wAll, QKV, 4096, 3072, 2048);

    // K-rope + V-transpose in one launch
    ropeKT_kernel<<<2560, 256, 0, stream>>>(QKV, Vt, ct, st);

    attn_kernel<<<dim3(16, 16, 2), 512, 0, stream>>>(QKV, Vt, AO, ct, st);

    // out = AO @ woT^T
    gemm_bt_kernel<false><<<dim3(16, 32), 256, 0, stream>>>(AO, woT, out, 4096, 2048, 2048);
}

// Round 12
// 177.112 us; speedup vs baseline: 1.0220x; 1.0220x over previous
//
#include <hip/hip_runtime.h>
#include <math.h>

// ---------------------------------------------------------------------------
// SlidingWindowGQA: x[2,2048,2048] f32, wq[2048,2048], wk/wv[2048,512], wo[2048,2048]
// out f32 [2,2048,2048].  B=2 S=2048 H=16 KVH=4 D=128 WINDOW=512.
// R12: R11 with the grid-decode bug fixed: unique work = 512 blocks (16 q x
//      4 heads-per-kvh x 8 (kvh,b) groups), not 1024. bid=i*8+g8 keeps all 64
//      blocks sharing one (b,kvh) KV panel on one XCD (round-robin bid%8).
// ---------------------------------------------------------------------------

typedef unsigned short u16;
typedef __attribute__((ext_vector_type(4))) float f32x4;
typedef __attribute__((ext_vector_type(8))) __bf16 bf16x8;
typedef __attribute__((ext_vector_type(4))) __bf16 bf16x4;
typedef __attribute__((ext_vector_type(4))) short s16x4;
typedef __attribute__((ext_vector_type(8))) unsigned short u16x8;
typedef __attribute__((ext_vector_type(4))) unsigned short u16x4;

#define DEV static __device__ __forceinline__

DEV float bf2f(u16 h) {
    union { unsigned int i; float f; } x;
    x.i = ((unsigned int)h) << 16;
    return x.f;
}
DEV u16 f2bf(float f) {
    union { float f; unsigned int i; } x;
    x.f = f;
    unsigned int u = x.i;
    return (u16)((u + 0x7FFFu + ((u >> 16) & 1u)) >> 16);
}

DEV f32x4 mfma32(bf16x8 a, bf16x8 b, f32x4 c) {
    return __builtin_amdgcn_mfma_f32_16x16x32_bf16(a, b, c, 0, 0, 0);
}
DEV f32x4 mfma16(bf16x4 a, bf16x4 b, f32x4 c) {
#if __has_builtin(__builtin_amdgcn_mfma_f32_16x16x16_bf16)
    return __builtin_amdgcn_mfma_f32_16x16x16_bf16(a, b, c, 0, 0, 0);
#else
    union { bf16x4 v; s16x4 s; } ua, ub;
    ua.v = a; ub.v = b;
    return __builtin_amdgcn_mfma_f32_16x16x16bf16_1k(ua.s, ub.s, c, 0, 0, 0);
#endif
}

DEV void gload_lds16(const void* g, void* lds) {
    __builtin_amdgcn_global_load_lds(
        (const __attribute__((address_space(1))) unsigned int*)g,
        (__attribute__((address_space(3))) unsigned int*)lds, 16, 0, 0);
}

// ---------------------------------------------------------------------------
// Fused prep: sincos table + x->bf16 cast + 4x weight convert/transpose.
__global__ __launch_bounds__(256) void prep_kernel(const float* x, const float* wq,
                                                   const float* wk, const float* wv,
                                                   const float* wo, u16* xb, u16* wAll,
                                                   u16* woT, float* ct, float* st) {
    __shared__ float tile[32][33];
    const int bid = blockIdx.x;
    const int tid = threadIdx.x;
    if (bid < 512) {
        int idx = bid * 256 + tid;                 // 131072
        int s = idx >> 6, d = idx & 63;
        float inv = exp2f(-(float)d * (13.287712379549449f / 64.f));
        float a = (float)s * inv;
        float sv, cv;
        sincosf(a, &sv, &cv);
        ct[idx] = cv;
        st[idx] = sv;
        return;
    }
    if (bid < 8704) {
        int i = (bid - 512) * 256 + tid;           // 2097152 float4s
        float4 v = ((const float4*)x)[i];
        u16x4 o;
        o[0] = f2bf(v.x); o[1] = f2bf(v.y); o[2] = f2bf(v.z); o[3] = f2bf(v.w);
        ((u16x4*)xb)[i] = o;
        return;
    }
    // convT: f32 [R][C](ldi) -> bf16 [C][R](ld 2048)
    int r = bid - 8704;
    const float* in;
    u16* out;
    int ldi, bx, by;
    if (r < 4096) { in = wq; out = wAll; ldi = 2048; bx = r & 63; by = r >> 6; }
    else if (r < 5120) { r -= 4096; in = wk; out = wAll + (long)2048 * 2048; ldi = 512; bx = r & 15; by = r >> 4; }
    else if (r < 6144) { r -= 5120; in = wv; out = wAll + (long)2560 * 2048; ldi = 512; bx = r & 15; by = r >> 4; }
    else { r -= 6144; in = wo; out = woT; ldi = 2048; bx = r & 63; by = r >> 6; }
    int cc = tid & 31, rb = tid >> 5;
    long r0 = (long)by * 32, c0 = (long)bx * 32;
#pragma unroll
    for (int i = 0; i < 4; i++)
        tile[rb + i * 8][cc] = in[(r0 + rb + i * 8) * (long)ldi + c0 + cc];
    __syncthreads();
#pragma unroll
    for (int i = 0; i < 4; i++)
        out[(c0 + rb + i * 8) * 2048L + r0 + cc] = f2bf(tile[cc][rb + i * 8]);
}

// Merged K-RoPE + V-transpose (Q-rope lives in attn).
__global__ __launch_bounds__(256) void ropeKT_kernel(u16* QKV, u16* Vt,
                                                     const float* ct, const float* st) {
    __shared__ u16 tile[32][33];
    const int bid = blockIdx.x;
    const int tid = threadIdx.x;
    if (bid < 512) {
        int idx = bid * 256 + tid;                 // 131072
        int m = idx >> 5;
        int rest = idx & 31;
        int hoff = 2048 + (rest >> 3) * 128;
        int d0 = (rest & 7) * 8;
        int s = m & 2047;
        u16* p1 = QKV + (long)m * 3072 + hoff + d0;
        u16* p2 = p1 + 64;
        u16x8 v1 = *(const u16x8*)p1;
        u16x8 v2 = *(const u16x8*)p2;
        const float* cp = ct + s * 64 + d0;
        const float* sp = st + s * 64 + d0;
        u16x8 o1, o2;
#pragma unroll
        for (int j = 0; j < 8; j++) {
            float x1 = bf2f(v1[j]), x2 = bf2f(v2[j]);
            float cc = cp[j], ss = sp[j];
            o1[j] = f2bf(x1 * cc - x2 * ss);
            o2[j] = f2bf(x2 * cc + x1 * ss);
        }
        *(u16x8*)p1 = o1;
        *(u16x8*)p2 = o2;
        return;
    }
    int r = bid - 512;                             // 2048 transpose blocks
    int z = r >> 10;
    int rr = r & 1023;
    int bx = rr & 15, by = rr >> 4;
    const u16* in = QKV + 2560 + (long)z * 2048 * 3072;
    u16* out = Vt + (long)z * 512 * 2048;
    int cc = tid & 31, rb = tid >> 5;
    long r0 = (long)by * 32, c0 = (long)bx * 32;
#pragma unroll
    for (int i = 0; i < 4; i++)
        tile[rb + i * 8][cc] = in[(r0 + rb + i * 8) * 3072 + c0 + cc];
    __syncthreads();
#pragma unroll
    for (int i = 0; i < 4; i++)
        out[(c0 + rb + i * 8) * 2048L + r0 + cc] = tile[cc][rb + i * 8];
}

// ---------------------------------------------------------------------------
// GEMM (R1/R8/R9 proven, untouched): C = A[M][K] * Bt[N][K]^T, 128x128, BK=32,
// 4 waves, 2-buffer LDS, global_load_lds(16B), XOR-swizzled (2-way free).
template <bool OUT_BF16>
__global__ __launch_bounds__(256) void gemm_bt_kernel(const u16* A, const u16* Bt, void* Cout,
                                                      int M, int N, int K) {
    __shared__ u16 As[2][128 * 32];
    __shared__ u16 Bs[2][128 * 32];
    const int tid = threadIdx.x;
    const int w = tid >> 6, l = tid & 63, g = l >> 4, c = l & 15;
    const int wm = w >> 1, wn = w & 1;
    const long m0 = (long)blockIdx.y * 128, n0 = (long)blockIdx.x * 128;
    const int nk = K >> 5;

    f32x4 acc[4][4];
    const f32x4 zero = {0.f, 0.f, 0.f, 0.f};
#pragma unroll
    for (int i = 0; i < 4; i++)
#pragma unroll
        for (int j = 0; j < 4; j++) acc[i][j] = zero;

    auto stage = [&](int buf, int kt) {
#pragma unroll
        for (int i = 0; i < 2; i++) {
            int o = (i * 256 + tid) * 16;
            int row = o >> 6;
            int cl = ((o >> 4) & 3) ^ ((row >> 1) & 3);
            gload_lds16(A + (m0 + row) * (long)K + kt * 32 + cl * 8,
                        (void*)&As[buf][(i * 256 + w * 64) * 8]);
        }
#pragma unroll
        for (int i = 0; i < 2; i++) {
            int o = (i * 256 + tid) * 16;
            int row = o >> 6;
            int cl = ((o >> 4) & 3) ^ ((row >> 1) & 3);
            gload_lds16(Bt + (n0 + row) * (long)K + kt * 32 + cl * 8,
                        (void*)&Bs[buf][(i * 256 + w * 64) * 8]);
        }
    };

    stage(0, 0);
    __syncthreads();
    int buf = 0;
    for (int kt = 0; kt < nk; ++kt) {
        if (kt + 1 < nk) stage(buf ^ 1, kt + 1);
        bf16x8 af[4], bf[4];
#pragma unroll
        for (int i = 0; i < 4; i++) {
            int rowa = wm * 64 + i * 16 + c;
            int cha = g ^ ((rowa >> 1) & 3);
            af[i] = *(const bf16x8*)&As[buf][rowa * 32 + cha * 8];
            int rowb = wn * 64 + i * 16 + c;
            int chb = g ^ ((rowb >> 1) & 3);
            bf[i] = *(const bf16x8*)&Bs[buf][rowb * 32 + chb * 8];
        }
#pragma unroll
        for (int i = 0; i < 4; i++)
#pragma unroll
            for (int j = 0; j < 4; j++) acc[i][j] = mfma32(af[i], bf[j], acc[i][j]);
        __syncthreads();
        buf ^= 1;
    }

#pragma unroll
    for (int i = 0; i < 4; i++)
#pragma unroll
        for (int j = 0; j < 4; j++) {
            long row0 = m0 + wm * 64 + i * 16 + g * 4;
            long col = n0 + wn * 64 + j * 16 + c;
#pragma unroll
            for (int r = 0; r < 4; r++) {
                float v = acc[i][j][r];
                if (OUT_BF16)
                    ((u16*)Cout)[(row0 + r) * (long)N + col] = f2bf(v);
                else
                    ((float*)Cout)[(row0 + r) * (long)N + col] = v;
            }
        }
}

// ---------------------------------------------------------------------------
// Flash sliding-window GQA (R9 body) with XCD-locality grid swizzle:
// flat 512 blocks, bid = i8*8 + g8, g8 = (kvh<<1)|b, i8 = hh*16 + qtile.
// Round-robin block->XCD puts all 64 blocks sharing one (b,kvh) KV panel
// (1MB, L2-fits) on one XCD.
#define ATT_SCALE 0.08838834764831845f
#define L2E 1.4426950408889634f

__global__ __launch_bounds__(512) void attn_kernel(const u16* QKV, const u16* Vt, u16* AO,
                                                   const float* ct, const float* st) {
    __shared__ u16 Ks[2][64 * 128];
    __shared__ u16 Vs[2][128 * 64];
    const int tid = threadIdx.x;
    const int w = tid >> 6, l = tid & 63, g = l >> 4, c = l & 15;
    // --- XCD-locality decode (512 blocks total) ---
    const int bid = blockIdx.x;
    const int g8 = bid & 7;
    const int b = g8 & 1;
    const int kvh = g8 >> 1;
    const int i8 = bid >> 3;                       // [0,64)
    const int q0 = (i8 & 15) * 128;
    const int h = kvh * 4 + (i8 >> 4);             // i8>>4 in [0,4)
    const int qb = q0 + w * 16;

    bf16x8 bq[4];
    {
        const u16* qrow = QKV + (long)(b * 2048 + qb + c) * 3072 + h * 128;
#pragma unroll
        for (int kc = 0; kc < 4; kc++) bq[kc] = *(const bf16x8*)(qrow + kc * 32 + g * 8);
        const float* cb = ct + (qb + c) * 64 + g * 8;
        const float* sb = st + (qb + c) * 64 + g * 8;
#pragma unroll
        for (int kc = 0; kc < 2; kc++) {
            union { bf16x8 v; u16x8 u; } lo, hi;
            lo.v = bq[kc]; hi.v = bq[kc + 2];
#pragma unroll
            for (int j = 0; j < 8; j++) {
                float x1 = bf2f(lo.u[j]), x2 = bf2f(hi.u[j]);
                float cc = cb[kc * 32 + j], ss = sb[kc * 32 + j];
                lo.u[j] = f2bf(x1 * cc - x2 * ss);
                hi.u[j] = f2bf(x2 * cc + x1 * ss);
            }
            bq[kc] = lo.v; bq[kc + 2] = hi.v;
        }
    }

    f32x4 acc_o[8];
    const f32x4 zero = {0.f, 0.f, 0.f, 0.f};
#pragma unroll
    for (int i = 0; i < 8; i++) acc_o[i] = zero;
    float m_run = -3.0e38f, l_run = 0.f;

    const int t_lo = (q0 > 511) ? ((q0 - 511) >> 6) : 0;
    const int t_hi = (q0 + 127) >> 6;

    auto stage = [&](int sb_, int t) {
        const int kv0 = t * 64;
#pragma unroll
        for (int i = 0; i < 2; i++) {
            int o = (i * 512 + tid) * 16;
            int key = o >> 8;
            int cl = ((o >> 4) & 15) ^ (key & 15);
            gload_lds16(QKV + (long)(b * 2048 + kv0 + key) * 3072 + 2048 + kvh * 128 + cl * 8,
                        (void*)&Ks[sb_][(i * 512 + w * 64) * 8]);
        }
#pragma unroll
        for (int i = 0; i < 2; i++) {
            int o = (i * 512 + tid) * 16;
            int d = o >> 7;
            int cl = ((o >> 4) & 7) ^ (d & 7);
            gload_lds16(Vt + (long)((b * 4 + kvh) * 128 + d) * 2048 + kv0 + cl * 8,
                        (void*)&Vs[sb_][(i * 512 + w * 64) * 8]);
        }
    };

    stage(0, t_lo);
    __syncthreads();
    int buf = 0;

    for (int t = t_lo; t <= t_hi; ++t) {
        const int kv0 = t * 64;
        if (t < t_hi) stage(buf ^ 1, t + 1);

        const bool active = (kv0 <= qb + 15) && (kv0 + 63 >= qb - 511);
        if (active) {
            f32x4 sacc[4];
#pragma unroll
            for (int n = 0; n < 4; n++) {
                sacc[n] = zero;
#pragma unroll
                for (int kc = 0; kc < 4; kc++) {
                    int row = n * 16 + c;
                    int ch = (kc * 4 + g) ^ c;
                    bf16x8 kf = *(const bf16x8*)&Ks[buf][row * 128 + ch * 8];
                    sacc[n] = mfma32(kf, bq[kc], sacc[n]);
                }
            }

            const bool edge = (kv0 + 63 > qb) || (kv0 < qb + 15 - 511);
            float p[4][4];
            float m_tile = -3.0e38f;
#pragma unroll
            for (int n = 0; n < 4; n++)
#pragma unroll
                for (int r = 0; r < 4; r++) {
                    float s = sacc[n][r] * ATT_SCALE;
                    if (edge) {
                        int j = kv0 + n * 16 + 4 * g + r;
                        int q = qb + c;
                        if (j > q || j < q - 511) s = -__builtin_inff();
                    }
                    p[n][r] = s;
                    m_tile = fmaxf(m_tile, s);
                }
            m_tile = fmaxf(m_tile, __shfl_xor(m_tile, 16));
            m_tile = fmaxf(m_tile, __shfl_xor(m_tile, 32));

            const bool keep = __all(m_tile - m_run <= 8.f);
            const float m_new = keep ? m_run : fmaxf(m_run, m_tile);

            float lsum = 0.f;
#pragma unroll
            for (int n = 0; n < 4; n++)
#pragma unroll
                for (int r = 0; r < 4; r++) {
                    float e = exp2f((p[n][r] - m_new) * L2E);
                    p[n][r] = e;
                    lsum += e;
                }
            lsum += __shfl_xor(lsum, 16);
            lsum += __shfl_xor(lsum, 32);

            if (!keep) {
                float alpha = exp2f((m_run - m_new) * L2E);
                l_run = l_run * alpha + lsum;
                m_run = m_new;
                float alpha_r[4];
#pragma unroll
                for (int r = 0; r < 4; r++) alpha_r[r] = __shfl(alpha, (g << 4) + 4 * g + r);
#pragma unroll
                for (int dn = 0; dn < 8; dn++) {
                    f32x4 t2 = acc_o[dn];
                    t2[0] *= alpha_r[0]; t2[1] *= alpha_r[1];
                    t2[2] *= alpha_r[2]; t2[3] *= alpha_r[3];
                    acc_o[dn] = t2;
                }
            } else {
                l_run += lsum;
            }

            bf16x4 ap[4];
#pragma unroll
            for (int n = 0; n < 4; n++) {
                union { u16x4 u; bf16x4 b; } pk;
                pk.u[0] = f2bf(p[n][0]); pk.u[1] = f2bf(p[n][1]);
                pk.u[2] = f2bf(p[n][2]); pk.u[3] = f2bf(p[n][3]);
                ap[n] = pk.b;
            }

#pragma unroll
            for (int n = 0; n < 4; n++)
#pragma unroll
                for (int dn = 0; dn < 8; dn++) {
                    int row = dn * 16 + c;
                    int ch = (2 * n + (g >> 1)) ^ (c & 7);
                    bf16x4 vf = *(const bf16x4*)&Vs[buf][row * 64 + ch * 8 + (g & 1) * 4];
                    acc_o[dn] = mfma16(ap[n], vf, acc_o[dn]);
                }
        }
        __syncthreads();
        buf ^= 1;
    }

    float lr[4];
#pragma unroll
    for (int r = 0; r < 4; r++) {
        float lq = __shfl(l_run, (g << 4) + 4 * g + r);
        lr[r] = 1.f / lq;
    }
#pragma unroll
    for (int dn = 0; dn < 8; dn++)
#pragma unroll
        for (int r = 0; r < 4; r++) {
            long row = (long)(b * 2048 + qb + 4 * g + r);
            AO[row * 2048 + h * 128 + dn * 16 + c] = f2bf(acc_o[dn][r] * lr[r]);
        }
}

// ---------------------------------------------------------------------------
extern "C" void kernel_launch(void* const* d_in, const int* in_sizes, int n_in,
                              void* d_out, int out_size, void* d_ws, size_t ws_size,
                              hipStream_t stream) {
    const float* x = (const float*)d_in[0];
    const float* wq = (const float*)d_in[1];
    const float* wk = (const float*)d_in[2];
    const float* wv = (const float*)d_in[3];
    const float* wo = (const float*)d_in[4];
    float* out = (float*)d_out;

    char* ws = (char*)d_ws;
    u16* xb = (u16*)(ws);                         // [4096][2048]        16.78 MB
    u16* wAll = (u16*)(ws + 16777216);            // [3072][2048] (BT)   12.58 MB
    u16* woT = (u16*)(ws + 29360128);             // [2048][2048] (BT)    8.39 MB
    u16* QKV = (u16*)(ws + 37748736);             // [4096][3072]        25.17 MB
    u16* Vt = (u16*)(ws + 62914560);              // [1024][2048]         4.19 MB
    u16* AO = (u16*)(ws + 67108864);              // [4096][2048]        16.78 MB
    float* ct = (float*)(ws + 83886080);          // [2048][64]
    float* st = (float*)(ws + 84410368);          // [2048][64]

    prep_kernel<<<18944, 256, 0, stream>>>(x, wq, wk, wv, wo, xb, wAll, woT, ct, st);

    // QKV = xb @ wAll^T
    gemm_bt_kernel<true><<<dim3(24, 32), 256, 0, stream>>>(xb, wAll, QKV, 4096, 3072, 2048);

    // K-rope + V-transpose in one launch
    ropeKT_kernel<<<2560, 256, 0, stream>>>(QKV, Vt, ct, st);

    // flat grid, XCD-locality swizzle (512 blocks = 16q x 4h x 8 (kvh,b))
    attn_kernel<<<512, 512, 0, stream>>>(QKV, Vt, AO, ct, st);

    // out = AO @ woT^T
    gemm_bt_kernel<false><<<dim3(16, 32), 256, 0, stream>>>(AO, woT, out, 4096, 2048, 2048);
}